// Round 1
// baseline (323.662 us; speedup 1.0000x reference)
//
#include <hip/hip_runtime.h>

#define N_NODES 30000
#define N_EDGES 150000
#define N_REL 10
#define DIM 256

#define SORT_BLOCKS 120
#define SORT_CHUNK ((N_EDGES + SORT_BLOCKS - 1) / SORT_BLOCKS)  // 1250

#define SCAN_CHUNK 256
#define SCAN_BLOCKS ((N_NODES + SCAN_CHUNK - 1) / SCAN_CHUNK)   // 118

// LDS A-tile row stride: 280 shorts = 560 B (16B-aligned, breaks pow2 banks)
#define A_STRIDE 280

// prep kernel block ranges
#define PREP_XB 7500   // conv_x: 30000*256/4/256
#define PREP_WB 5376   // conv_w: 21*65536/256
#define PREP_ZB 235    // zero cnt: (60000+255)/256

typedef __attribute__((ext_vector_type(8))) short bf16x8;
typedef __attribute__((ext_vector_type(4))) float f32x4;

__device__ __forceinline__ unsigned short f2bf(float f) {
  union { float f; unsigned int u; } v; v.f = f;
  unsigned int u = v.u;
  unsigned int r = u + 0x7fffu + ((u >> 16) & 1u);  // RNE
  return (unsigned short)(r >> 16);
}

// ---- fused preprocessing: x->bf16, W->bf16 transposed, zero cnt ----------

__global__ void prep_kernel(const float* __restrict__ x,
                            const float* __restrict__ Wf,
                            const float* __restrict__ Wr,
                            const float* __restrict__ Ws,
                            unsigned short* __restrict__ xbf,
                            unsigned short* __restrict__ wt,
                            int* __restrict__ cnt) {
  int b = blockIdx.x;
  if (b < PREP_XB) {
    int idx = b * 256 + threadIdx.x;  // one float4 each, exact
    float4 v = reinterpret_cast<const float4*>(x)[idx];
    ushort4 o;
    o.x = f2bf(v.x); o.y = f2bf(v.y); o.z = f2bf(v.z); o.w = f2bf(v.w);
    reinterpret_cast<ushort4*>(xbf)[idx] = o;
  } else if (b < PREP_XB + PREP_WB) {
    int idx = (b - PREP_XB) * 256 + threadIdx.x;  // wt[b][o][i] = W_b[i][o]
    int bb = idx >> 16;
    int t = idx & 65535;
    int o = t >> 8, i = t & 255;
    const float* src = (bb < N_REL) ? (Wf + (size_t)bb * 65536)
                     : (bb < 2 * N_REL) ? (Wr + (size_t)(bb - N_REL) * 65536)
                     : Ws;
    wt[idx] = f2bf(src[i * 256 + o]);
  } else {
    int i = (b - PREP_XB - PREP_WB) * 256 + threadIdx.x;
    if (i < 2 * N_NODES) cnt[i] = 0;
  }
}

// one edge pass: per-block rel histogram (LDS) + global dst histograms
__global__ void hist_all_kernel(const int* __restrict__ rel,
                                const int* __restrict__ dep,
                                const int* __restrict__ gov,
                                int* __restrict__ block_counts,
                                int* __restrict__ cnt) {
  __shared__ int h[N_REL];
  if (threadIdx.x < N_REL) h[threadIdx.x] = 0;
  __syncthreads();
  int beg = blockIdx.x * SORT_CHUNK;
  int end = min(beg + SORT_CHUNK, N_EDGES);
  for (int e = beg + threadIdx.x; e < end; e += blockDim.x) {
    atomicAdd(&h[rel[e]], 1);
    atomicAdd(&cnt[dep[e]], 1);             // 30k bins: low contention
    atomicAdd(&cnt[N_NODES + gov[e]], 1);
  }
  __syncthreads();
  if (threadIdx.x < N_REL)
    block_counts[blockIdx.x * N_REL + threadIdx.x] = h[threadIdx.x];
}

__global__ void scan_rel_kernel(const int* __restrict__ block_counts,
                                int* __restrict__ rel_start,
                                int* __restrict__ block_offset) {
  __shared__ int tot[N_REL];
  int r = threadIdx.x;
  if (r < N_REL) {
    int s = 0;
    for (int b = 0; b < SORT_BLOCKS; ++b) s += block_counts[b * N_REL + r];
    tot[r] = s;
  }
  __syncthreads();
  if (threadIdx.x == 0) {
    int s = 0;
    for (int i = 0; i < N_REL; ++i) { rel_start[i] = s; s += tot[i]; }
    rel_start[N_REL] = s;
  }
  __syncthreads();
  if (r < N_REL) {
    int run = rel_start[r];
    for (int b = 0; b < SORT_BLOCKS; ++b) {
      block_offset[b * N_REL + r] = run;
      run += block_counts[b * N_REL + r];
    }
  }
}

__global__ void scanA_kernel(const int* __restrict__ cnt,
                             int* __restrict__ tmp, int* __restrict__ sums) {
  __shared__ int s[SCAN_CHUNK];
  int d = blockIdx.y, b = blockIdx.x, t = threadIdx.x;
  int i = b * SCAN_CHUNK + t;
  int v = (i < N_NODES) ? cnt[d * N_NODES + i] : 0;
  s[t] = v;
  __syncthreads();
  for (int off = 1; off < SCAN_CHUNK; off <<= 1) {
    int add = (t >= off) ? s[t - off] : 0;
    __syncthreads();
    s[t] += add;
    __syncthreads();
  }
  if (i < N_NODES) tmp[d * N_NODES + i] = s[t] - v;  // exclusive
  if (t == SCAN_CHUNK - 1) sums[d * SCAN_BLOCKS + b] = s[t];
}

__global__ void scanB_kernel(const int* __restrict__ sums,
                             int* __restrict__ chunk_off, int* __restrict__ rp) {
  __shared__ int s[128];
  int d = blockIdx.x, t = threadIdx.x;
  int v = (t < SCAN_BLOCKS) ? sums[d * SCAN_BLOCKS + t] : 0;
  s[t] = v;
  __syncthreads();
  for (int off = 1; off < 128; off <<= 1) {
    int add = (t >= off) ? s[t - off] : 0;
    __syncthreads();
    s[t] += add;
    __syncthreads();
  }
  if (t < SCAN_BLOCKS) chunk_off[d * SCAN_BLOCKS + t] = s[t] - v;
  if (t == 127) rp[d * (N_NODES + 1) + N_NODES] = s[127];
}

__global__ void scanC_kernel(const int* __restrict__ tmp,
                             const int* __restrict__ chunk_off,
                             int* __restrict__ rp, int* __restrict__ cursor) {
  int d = blockIdx.y;
  int i = blockIdx.x * SCAN_CHUNK + threadIdx.x;
  if (i < N_NODES) {
    int v = tmp[d * N_NODES + i] + chunk_off[d * SCAN_BLOCKS + blockIdx.x];
    rp[d * (N_NODES + 1) + i] = v;
    cursor[d * N_NODES + i] = v;
  }
}

// rel-scatter producing perm, per-slot SOURCE node ids (srcf/srcr), AND the
// dst-keyed col lists in one pass
__global__ void scatter_all_kernel(const int* __restrict__ rel,
                                   const int* __restrict__ dep,
                                   const int* __restrict__ gov,
                                   const int* __restrict__ block_offset,
                                   int* __restrict__ cursor,
                                   int* __restrict__ perm,
                                   int* __restrict__ srcf,
                                   int* __restrict__ srcr,
                                   int* __restrict__ colf,
                                   int* __restrict__ colr) {
  __shared__ int cur[N_REL];
  if (threadIdx.x < N_REL)
    cur[threadIdx.x] = block_offset[blockIdx.x * N_REL + threadIdx.x];
  __syncthreads();
  int beg = blockIdx.x * SORT_CHUNK;
  int end = min(beg + SORT_CHUNK, N_EDGES);
  for (int e = beg + threadIdx.x; e < end; e += blockDim.x) {
    int dp = dep[e], gv = gov[e];
    int pos = atomicAdd(&cur[rel[e]], 1);  // LDS atomic, cheap
    perm[pos] = e;
    srcf[pos] = gv;   // fwd msg source = governor
    srcr[pos] = dp;   // rev msg source = dependent
    colf[atomicAdd(&cursor[dp], 1)] = pos;             // fwd msg pos -> dep
    colr[atomicAdd(&cursor[N_NODES + gv], 1)] = pos;   // rev msg pos -> gov
  }
}

// ---- mega GEMM: buckets 0..9 fwd-edge, 10..19 rev-edge, 20/21 self -------
// Edge buckets write bf16 msg rows (linear slots) in C/D-permuted column
// order: short at row*DIM + nb + lm*4 + i holds col nb + i*16 + lm.
// Self buckets (split in two for load balance) write fp32 directly to out.
// Software-pipelined (T14): tile t+1's gather loads are issued into VGPRs
// before computing tile t; ds_write lands at the top of the next iteration.
// Source indices come precomputed per msg slot (srcf/srcr) and are
// prefetched one further tile ahead.

__global__ __launch_bounds__(256, 2)
void mega_gemm_kernel(const unsigned short* __restrict__ xbf,
                      const unsigned short* __restrict__ wt,
                      const float* __restrict__ b_self,
                      const float* __restrict__ b_fwd,
                      const float* __restrict__ b_rev,
                      const int* __restrict__ srcf,
                      const int* __restrict__ srcr,
                      const int* __restrict__ rel_start,
                      unsigned short* __restrict__ msg,
                      float* __restrict__ out) {
  const int bkt = blockIdx.y;
  const bool is_self = (bkt >= 2 * N_REL);
  const bool fwd = bkt < N_REL;
  const int r = is_self ? 0 : (fwd ? bkt : bkt - N_REL);

  int beg, cnt;
  const int* src_arr = fwd ? srcf : srcr;
  unsigned short* mdir = msg + (fwd ? 0 : (size_t)N_EDGES * DIM);
  if (is_self) {
    beg = (bkt - 2 * N_REL) * (N_NODES / 2);  // 0 or 15000
    cnt = N_NODES / 2;
  } else {
    beg = rel_start[r];
    cnt = rel_start[r + 1] - beg;
  }
  const int ntiles = (cnt + 63) >> 6;
  const int GX = gridDim.x;

  const int tid = threadIdx.x;
  const int wave = tid >> 6, lane = tid & 63;
  const int lm = lane & 15, q = lane >> 4;
  const int nb = wave * 64;
  const int half = lane >> 5;      // 0 or 1
  const int lcol = lane & 31;      // 16B chunk index within row

  __shared__ int s_src[64];
  __shared__ unsigned short sA[64 * A_STRIDE];  // 35840 B

  // hoisted, tile-invariant W fragments (128 VGPRs)
  bf16x8 wf[8][4];
  const unsigned short* wbase = wt + (size_t)(is_self ? 2 * N_REL : bkt) * DIM * DIM;
  #pragma unroll
  for (int kk = 0; kk < 8; ++kk)
    #pragma unroll
    for (int ni = 0; ni < 4; ++ni)
      wf[kk][ni] = *reinterpret_cast<const bf16x8*>(
          wbase + (size_t)(nb + ni * 16 + lm) * DIM + kk * 32 + q * 8);

  const float* bptr = is_self ? b_self : ((fwd ? b_fwd : b_rev) + r * DIM);
  float bias[4];
  #pragma unroll
  for (int ni = 0; ni < 4; ++ni) bias[ni] = bptr[nb + ni * 16 + lm];

  int t = blockIdx.x;
  if (t >= ntiles) return;  // uniform over block: safe w.r.t. barriers

  // idx fetch for tile tt into reg (tid<64 lanes only)
  auto load_idx = [&](int tt) -> int {
    int tile0_ = tt << 6;
    if (is_self) {
      int rr = beg + tile0_ + tid;
      return rr < beg + cnt ? rr : beg + cnt - 1;
    } else {
      int p_ = tile0_ + tid;
      p_ = p_ < cnt ? p_ : cnt - 1;
      return src_arr[beg + p_];
    }
  };
  // issue next tile's gathered rows into regs (global loads, no LDS write yet)
  auto issue_D = [&](uint4* d) {
    #pragma unroll
    for (int i = 0; i < 8; ++i) {
      int row = wave * 16 + i * 2 + half;
      d[i] = *reinterpret_cast<const uint4*>(
          xbf + (size_t)s_src[row] * DIM + lcol * 8);
    }
  };
  auto write_A = [&](const uint4* d) {
    #pragma unroll
    for (int i = 0; i < 8; ++i) {
      int row = wave * 16 + i * 2 + half;
      *reinterpret_cast<uint4*>(sA + row * A_STRIDE + lcol * 8) = d[i];
    }
  };

  // ---- pipeline prologue: I(t) -> s_src; D(t) -> regs; I(t+GX) -> reg ----
  int idxreg = 0;
  if (tid < 64) s_src[tid] = load_idx(t);
  __syncthreads();
  uint4 d[8];
  issue_D(d);
  if (tid < 64 && t + GX < ntiles) idxreg = load_idx(t + GX);

  for (; t < ntiles; t += GX) {
    const int tile0 = t << 6;
    const int rows_valid = min(64, cnt - tile0);
    const bool have_next = (t + GX) < ntiles;
    const bool have_next2 = (t + 2 * GX) < ntiles;

    __syncthreads();  // prior iter's sA reads + s_src reads complete
    if (tid < 64 && have_next) s_src[tid] = idxreg;  // I(t+GX) -> LDS
    write_A(d);                                      // D(t): vmcnt + ds_write
    if (tid < 64 && have_next2) idxreg = load_idx(t + 2 * GX);
    __syncthreads();  // sA + s_src ready
    if (have_next) issue_D(d);  // D(t+GX) in flight under compute

    f32x4 acc[4][4];
    #pragma unroll
    for (int mi = 0; mi < 4; ++mi)
      #pragma unroll
      for (int ni = 0; ni < 4; ++ni)
        acc[mi][ni] = (f32x4){0.f, 0.f, 0.f, 0.f};

    // pure LDS-read + MFMA k-loop (W is in registers)
    #pragma unroll
    for (int kk = 0; kk < 8; ++kk) {
      bf16x8 a[4];
      #pragma unroll
      for (int mi = 0; mi < 4; ++mi)
        a[mi] = *reinterpret_cast<const bf16x8*>(
            sA + (mi * 16 + lm) * A_STRIDE + kk * 32 + q * 8);
      #pragma unroll
      for (int mi = 0; mi < 4; ++mi)
        #pragma unroll
        for (int ni = 0; ni < 4; ++ni)
          acc[mi][ni] = __builtin_amdgcn_mfma_f32_16x16x32_bf16(a[mi], wf[kk][ni], acc[mi][ni], 0, 0, 0);
    }

    if (is_self) {
      // direct fp32 stores to out (C/D layout; row = quad*4 + reg)
      #pragma unroll
      for (int mi = 0; mi < 4; ++mi) {
        #pragma unroll
        for (int reg = 0; reg < 4; ++reg) {
          int row = mi * 16 + q * 4 + reg;
          if (row < rows_valid) {
            #pragma unroll
            for (int ni = 0; ni < 4; ++ni)
              out[(size_t)(beg + tile0 + row) * DIM + nb + ni * 16 + lm] =
                  acc[mi][ni][reg] + bias[ni];
          }
        }
      }
    } else {
      // permuted uint2 bf16 stores to linear msg slots
      #pragma unroll
      for (int mi = 0; mi < 4; ++mi) {
        #pragma unroll
        for (int reg = 0; reg < 4; ++reg) {
          int row = mi * 16 + q * 4 + reg;
          if (row < rows_valid) {
            unsigned int p0 = ((unsigned int)f2bf(acc[mi][1][reg] + bias[1]) << 16) |
                              f2bf(acc[mi][0][reg] + bias[0]);
            unsigned int p1 = ((unsigned int)f2bf(acc[mi][3][reg] + bias[3]) << 16) |
                              f2bf(acc[mi][2][reg] + bias[2]);
            uint2 u; u.x = p0; u.y = p1;
            *reinterpret_cast<uint2*>(
                mdir + (size_t)(beg + tile0 + row) * DIM + nb + lm * 4) = u;
          }
        }
      }
    }
  }
}

// ---- phase 2: CSR gather-sum, 4-row parallel, uint2 loads, permuted cols -

__global__ void reduce_both_kernel(const unsigned short* __restrict__ msg,
                                   const int* __restrict__ rp,
                                   const int* __restrict__ colf,
                                   const int* __restrict__ colr,
                                   float* __restrict__ out) {
  const int n = blockIdx.x, t = threadIdx.x;
  const int g = t >> 6, lane = t & 63;
  const int b0 = rp[n], e0 = rp[n + 1];
  const int b1 = rp[(N_NODES + 1) + n], e1 = rp[(N_NODES + 1) + n + 1];
  if (e0 <= b0 && e1 <= b1) return;

  float a0 = 0.f, a1 = 0.f, a2 = 0.f, a3 = 0.f;
  for (int j = b0 + g; j < e0; j += 4) {
    int row = colf[j];
    uint2 v = *reinterpret_cast<const uint2*>(msg + (size_t)row * DIM + lane * 4);
    union { unsigned int u; float f; } c;
    c.u = v.x << 16;          a0 += c.f;
    c.u = v.x & 0xffff0000u;  a1 += c.f;
    c.u = v.y << 16;          a2 += c.f;
    c.u = v.y & 0xffff0000u;  a3 += c.f;
  }
  for (int j = b1 + g; j < e1; j += 4) {
    int row = colr[j];
    uint2 v = *reinterpret_cast<const uint2*>(
        msg + (size_t)(N_EDGES + row) * DIM + lane * 4);
    union { unsigned int u; float f; } c;
    c.u = v.x << 16;          a0 += c.f;
    c.u = v.x & 0xffff0000u;  a1 += c.f;
    c.u = v.y << 16;          a2 += c.f;
    c.u = v.y & 0xffff0000u;  a3 += c.f;
  }

  // invert the storage permutation: short i of thread's uint2 is column
  // (lane>>4)*64 + i*16 + (lane&15)
  __shared__ float part[4][DIM];
  const int cb = (lane >> 4) * 64 + (lane & 15);
  part[g][cb +  0] = a0;
  part[g][cb + 16] = a1;
  part[g][cb + 32] = a2;
  part[g][cb + 48] = a3;
  __syncthreads();
  float s = part[0][t] + part[1][t] + part[2][t] + part[3][t];
  out[(size_t)n * DIM + t] += s;
}

// ---- fallback: single-phase atomic scatter (if ws too small) -------------

__global__ __launch_bounds__(256, 2)
void self_gemm_kernel(const unsigned short* __restrict__ xbf,
                      const unsigned short* __restrict__ wt_self,
                      const float* __restrict__ b_self,
                      float* __restrict__ out) {
  const int tid = threadIdx.x;
  const int wave = tid >> 6, lane = tid & 63;
  const int lm = lane & 15, q = lane >> 4;
  const int nb = wave * 64;

  bf16x8 wf[8][4];
  #pragma unroll
  for (int kk = 0; kk < 8; ++kk)
    #pragma unroll
    for (int ni = 0; ni < 4; ++ni)
      wf[kk][ni] = *reinterpret_cast<const bf16x8*>(
          wt_self + (size_t)(nb + ni * 16 + lm) * DIM + kk * 32 + q * 8);

  float bias[4];
  #pragma unroll
  for (int ni = 0; ni < 4; ++ni) bias[ni] = b_self[nb + ni * 16 + lm];

  const int ntiles = (N_NODES + 63) / 64;
  for (int t = blockIdx.x; t < ntiles; t += gridDim.x) {
    const int row0 = t * 64;
    const unsigned short* xr[4];
    #pragma unroll
    for (int mi = 0; mi < 4; ++mi) {
      int r = row0 + mi * 16 + lm;
      int rc = r < N_NODES ? r : N_NODES - 1;
      xr[mi] = xbf + (size_t)rc * DIM + q * 8;
    }

    f32x4 acc[4][4];
    #pragma unroll
    for (int mi = 0; mi < 4; ++mi)
      #pragma unroll
      for (int ni = 0; ni < 4; ++ni)
        acc[mi][ni] = (f32x4){0.f, 0.f, 0.f, 0.f};

    #pragma unroll
    for (int kk = 0; kk < 8; ++kk) {
      bf16x8 a[4];
      #pragma unroll
      for (int mi = 0; mi < 4; ++mi)
        a[mi] = *reinterpret_cast<const bf16x8*>(xr[mi] + kk * 32);
      #pragma unroll
      for (int mi = 0; mi < 4; ++mi)
        #pragma unroll
        for (int ni = 0; ni < 4; ++ni)
          acc[mi][ni] = __builtin_amdgcn_mfma_f32_16x16x32_bf16(a[mi], wf[kk][ni], acc[mi][ni], 0, 0, 0);
    }

    #pragma unroll
    for (int mi = 0; mi < 4; ++mi) {
      #pragma unroll
      for (int reg = 0; reg < 4; ++reg) {
        int row = row0 + mi * 16 + q * 4 + reg;
        if (row < N_NODES) {
          #pragma unroll
          for (int ni = 0; ni < 4; ++ni)
            out[(size_t)row * DIM + nb + ni * 16 + lm] = acc[mi][ni][reg] + bias[ni];
        }
      }
    }
  }
}

__global__ void edge_gemm_atomic_kernel(const unsigned short* __restrict__ xbf,
                                        const unsigned short* __restrict__ wt,
                                        const float* __restrict__ b_fwd,
                                        const float* __restrict__ b_rev,
                                        const int* __restrict__ perm,
                                        const int* __restrict__ rel_start,
                                        const int* __restrict__ dep,
                                        const int* __restrict__ gov,
                                        float* __restrict__ out) {
  const int bucket = blockIdx.y;
  const int r = bucket % N_REL;
  const bool fwd = bucket < N_REL;
  const int beg = rel_start[r];
  const int cnt = rel_start[r + 1] - beg;
  const int ntiles = (cnt + 63) >> 6;

  const int tid = threadIdx.x;
  const int wave = tid >> 6, lane = tid & 63;
  const int lm = lane & 15, q = lane >> 4;
  const int nb = wave * 64;

  __shared__ int s_src[64], s_dst[64];

  const unsigned short* wr[4];
  #pragma unroll
  for (int ni = 0; ni < 4; ++ni)
    wr[ni] = wt + (size_t)bucket * DIM * DIM + (size_t)(nb + ni * 16 + lm) * DIM + q * 8;

  const float* bptr = (fwd ? b_fwd : b_rev) + r * DIM;
  float bias[4];
  #pragma unroll
  for (int ni = 0; ni < 4; ++ni) bias[ni] = bptr[nb + ni * 16 + lm];

  for (int t = blockIdx.x; t < ntiles; t += gridDim.x) {
    const int tile0 = t << 6;
    const int rows_valid = min(64, cnt - tile0);

    if (tid < 64) {
      int s = 0, d = -1;
      if (tid < rows_valid) {
        int e = perm[beg + tile0 + tid];
        int gv = gov[e], dp = dep[e];
        s = fwd ? gv : dp;
        d = fwd ? dp : gv;
      }
      s_src[tid] = s;
      s_dst[tid] = d;
    }
    __syncthreads();

    const unsigned short* xr[4];
    #pragma unroll
    for (int mi = 0; mi < 4; ++mi)
      xr[mi] = xbf + (size_t)s_src[mi * 16 + lm] * DIM + q * 8;

    f32x4 acc[4][4];
    #pragma unroll
    for (int mi = 0; mi < 4; ++mi)
      #pragma unroll
      for (int ni = 0; ni < 4; ++ni)
        acc[mi][ni] = (f32x4){0.f, 0.f, 0.f, 0.f};

    #pragma unroll
    for (int k0 = 0; k0 < DIM; k0 += 32) {
      bf16x8 a[4], b[4];
      #pragma unroll
      for (int mi = 0; mi < 4; ++mi) a[mi] = *reinterpret_cast<const bf16x8*>(xr[mi] + k0);
      #pragma unroll
      for (int ni = 0; ni < 4; ++ni) b[ni] = *reinterpret_cast<const bf16x8*>(wr[ni] + k0);
      #pragma unroll
      for (int mi = 0; mi < 4; ++mi)
        #pragma unroll
        for (int ni = 0; ni < 4; ++ni)
          acc[mi][ni] = __builtin_amdgcn_mfma_f32_16x16x32_bf16(a[mi], b[ni], acc[mi][ni], 0, 0, 0);
    }

    #pragma unroll
    for (int mi = 0; mi < 4; ++mi) {
      #pragma unroll
      for (int reg = 0; reg < 4; ++reg) {
        int row = mi * 16 + q * 4 + reg;
        if (row < rows_valid) {
          int dst = s_dst[row];
          float* op = out + (size_t)dst * DIM + nb + lm;
          #pragma unroll
          for (int ni = 0; ni < 4; ++ni)
            atomicAdd(op + ni * 16, acc[mi][ni][reg] + bias[ni]);
        }
      }
    }
    __syncthreads();
  }
}

// ---- launch --------------------------------------------------------------

extern "C" void kernel_launch(void* const* d_in, const int* in_sizes, int n_in,
                              void* d_out, int out_size, void* d_ws, size_t ws_size,
                              hipStream_t stream) {
  const float* x      = (const float*)d_in[0];
  const float* W_self = (const float*)d_in[1];
  const float* b_self = (const float*)d_in[2];
  const float* W_fwd  = (const float*)d_in[3];
  const float* b_fwd  = (const float*)d_in[4];
  const float* W_rev  = (const float*)d_in[5];
  const float* b_rev  = (const float*)d_in[6];
  const int* dep = (const int*)d_in[7];
  const int* rel = (const int*)d_in[8];
  const int* gov = (const int*)d_in[9];
  float* out = (float*)d_out;

  char* base = (char*)d_ws;
  size_t off = 0;
  auto alloc = [&](size_t bytes) -> char* {
    char* p = base + off;
    off = (off + bytes + 15) & ~(size_t)15;
    return p;
  };

  unsigned short* xbf = (unsigned short*)alloc((size_t)N_NODES * DIM * 2);   // 15.36 MB
  unsigned short* wt  = (unsigned short*)alloc((size_t)21 * DIM * DIM * 2);  // 2.75 MB
  int* perm          = (int*)alloc((size_t)N_EDGES * 4);
  int* srcf          = (int*)alloc((size_t)N_EDGES * 4);
  int* srcr          = (int*)alloc((size_t)N_EDGES * 4);
  int* rel_start     = (int*)alloc(16 * 4);
  int* block_counts  = (int*)alloc(SORT_BLOCKS * N_REL * 4);
  int* block_offset  = (int*)alloc(SORT_BLOCKS * N_REL * 4);
  int* cnt       = (int*)alloc((size_t)2 * N_NODES * 4);
  int* tmp       = (int*)alloc((size_t)2 * N_NODES * 4);
  int* sums      = (int*)alloc((size_t)2 * SCAN_BLOCKS * 4);
  int* chunk_off = (int*)alloc((size_t)2 * SCAN_BLOCKS * 4);
  int* rp        = (int*)alloc((size_t)2 * (N_NODES + 1) * 4);
  int* cursor    = (int*)alloc((size_t)2 * N_NODES * 4);
  int* colf      = (int*)alloc((size_t)N_EDGES * 4);
  int* colr      = (int*)alloc((size_t)N_EDGES * 4);
  unsigned short* msg = (unsigned short*)alloc((size_t)2 * N_EDGES * DIM * 2);  // 153.6 MB
  const bool two_phase = (off <= ws_size);

  prep_kernel<<<PREP_XB + PREP_WB + PREP_ZB, 256, 0, stream>>>(
      x, W_fwd, W_rev, W_self, xbf, wt, cnt);
  hist_all_kernel<<<SORT_BLOCKS, 256, 0, stream>>>(rel, dep, gov, block_counts, cnt);
  scan_rel_kernel<<<1, 64, 0, stream>>>(block_counts, rel_start, block_offset);
  scanA_kernel<<<dim3(SCAN_BLOCKS, 2), SCAN_CHUNK, 0, stream>>>(cnt, tmp, sums);
  scanB_kernel<<<2, 128, 0, stream>>>(sums, chunk_off, rp);
  scanC_kernel<<<dim3(SCAN_BLOCKS, 2), SCAN_CHUNK, 0, stream>>>(tmp, chunk_off, rp, cursor);
  scatter_all_kernel<<<SORT_BLOCKS, 256, 0, stream>>>(
      rel, dep, gov, block_offset, cursor, perm, srcf, srcr, colf, colr);

  if (two_phase) {
    // buckets 0..19 edges -> msg; buckets 20/21 self halves -> out
    mega_gemm_kernel<<<dim3(48, 2 * N_REL + 2), 256, 0, stream>>>(
        xbf, wt, b_self, b_fwd, b_rev, srcf, srcr, rel_start, msg, out);
    reduce_both_kernel<<<N_NODES, 256, 0, stream>>>(msg, rp, colf, colr, out);
  } else {
    self_gemm_kernel<<<120, 256, 0, stream>>>(
        xbf, wt + (size_t)20 * DIM * DIM, b_self, out);
    edge_gemm_atomic_kernel<<<dim3(260, 20), 256, 0, stream>>>(
        xbf, wt, b_fwd, b_rev, perm, rel_start, dep, gov, out);
  }
}

// Round 2
// 288.304 us; speedup vs baseline: 1.1226x; 1.1226x over previous
//
#include <hip/hip_runtime.h>

#define N_NODES 30000
#define N_EDGES 150000
#define N_REL 10
#define DIM 256

#define SORT_BLOCKS 120
#define SORT_CHUNK ((N_EDGES + SORT_BLOCKS - 1) / SORT_BLOCKS)  // 1250

#define SCAN_CHUNK 256
#define SCAN_BLOCKS ((N_NODES + SCAN_CHUNK - 1) / SCAN_CHUNK)   // 118

// prep kernel block ranges
#define PREP_XB 7500   // conv_x: 30000*256/4/256
#define PREP_WB 5376   // conv_w: 21*65536/256
#define PREP_ZB 235    // zero cnt: (60000+255)/256

typedef __attribute__((ext_vector_type(8))) short bf16x8;
typedef __attribute__((ext_vector_type(4))) float f32x4;

__device__ __forceinline__ unsigned short f2bf(float f) {
  union { float f; unsigned int u; } v; v.f = f;
  unsigned int u = v.u;
  unsigned int r = u + 0x7fffu + ((u >> 16) & 1u);  // RNE
  return (unsigned short)(r >> 16);
}

// ---- fused preprocessing: x->bf16, W->bf16 transposed, zero cnt ----------

__global__ void prep_kernel(const float* __restrict__ x,
                            const float* __restrict__ Wf,
                            const float* __restrict__ Wr,
                            const float* __restrict__ Ws,
                            unsigned short* __restrict__ xbf,
                            unsigned short* __restrict__ wt,
                            int* __restrict__ cnt) {
  int b = blockIdx.x;
  if (b < PREP_XB) {
    int idx = b * 256 + threadIdx.x;  // one float4 each, exact
    float4 v = reinterpret_cast<const float4*>(x)[idx];
    ushort4 o;
    o.x = f2bf(v.x); o.y = f2bf(v.y); o.z = f2bf(v.z); o.w = f2bf(v.w);
    reinterpret_cast<ushort4*>(xbf)[idx] = o;
  } else if (b < PREP_XB + PREP_WB) {
    int idx = (b - PREP_XB) * 256 + threadIdx.x;  // wt[b][o][i] = W_b[i][o]
    int bb = idx >> 16;
    int t = idx & 65535;
    int o = t >> 8, i = t & 255;
    const float* src = (bb < N_REL) ? (Wf + (size_t)bb * 65536)
                     : (bb < 2 * N_REL) ? (Wr + (size_t)(bb - N_REL) * 65536)
                     : Ws;
    wt[idx] = f2bf(src[i * 256 + o]);
  } else {
    int i = (b - PREP_XB - PREP_WB) * 256 + threadIdx.x;
    if (i < 2 * N_NODES) cnt[i] = 0;
  }
}

// one edge pass: per-block rel histogram (LDS) + global dst histograms
__global__ void hist_all_kernel(const int* __restrict__ rel,
                                const int* __restrict__ dep,
                                const int* __restrict__ gov,
                                int* __restrict__ block_counts,
                                int* __restrict__ cnt) {
  __shared__ int h[N_REL];
  if (threadIdx.x < N_REL) h[threadIdx.x] = 0;
  __syncthreads();
  int beg = blockIdx.x * SORT_CHUNK;
  int end = min(beg + SORT_CHUNK, N_EDGES);
  for (int e = beg + threadIdx.x; e < end; e += blockDim.x) {
    atomicAdd(&h[rel[e]], 1);
    atomicAdd(&cnt[dep[e]], 1);             // 30k bins: low contention
    atomicAdd(&cnt[N_NODES + gov[e]], 1);
  }
  __syncthreads();
  if (threadIdx.x < N_REL)
    block_counts[blockIdx.x * N_REL + threadIdx.x] = h[threadIdx.x];
}

__global__ void scan_rel_kernel(const int* __restrict__ block_counts,
                                int* __restrict__ rel_start,
                                int* __restrict__ block_offset) {
  __shared__ int tot[N_REL];
  int r = threadIdx.x;
  if (r < N_REL) {
    int s = 0;
    for (int b = 0; b < SORT_BLOCKS; ++b) s += block_counts[b * N_REL + r];
    tot[r] = s;
  }
  __syncthreads();
  if (threadIdx.x == 0) {
    int s = 0;
    for (int i = 0; i < N_REL; ++i) { rel_start[i] = s; s += tot[i]; }
    rel_start[N_REL] = s;
  }
  __syncthreads();
  if (r < N_REL) {
    int run = rel_start[r];
    for (int b = 0; b < SORT_BLOCKS; ++b) {
      block_offset[b * N_REL + r] = run;
      run += block_counts[b * N_REL + r];
    }
  }
}

__global__ void scanA_kernel(const int* __restrict__ cnt,
                             int* __restrict__ tmp, int* __restrict__ sums) {
  __shared__ int s[SCAN_CHUNK];
  int d = blockIdx.y, b = blockIdx.x, t = threadIdx.x;
  int i = b * SCAN_CHUNK + t;
  int v = (i < N_NODES) ? cnt[d * N_NODES + i] : 0;
  s[t] = v;
  __syncthreads();
  for (int off = 1; off < SCAN_CHUNK; off <<= 1) {
    int add = (t >= off) ? s[t - off] : 0;
    __syncthreads();
    s[t] += add;
    __syncthreads();
  }
  if (i < N_NODES) tmp[d * N_NODES + i] = s[t] - v;  // exclusive
  if (t == SCAN_CHUNK - 1) sums[d * SCAN_BLOCKS + b] = s[t];
}

__global__ void scanB_kernel(const int* __restrict__ sums,
                             int* __restrict__ chunk_off, int* __restrict__ rp) {
  __shared__ int s[128];
  int d = blockIdx.x, t = threadIdx.x;
  int v = (t < SCAN_BLOCKS) ? sums[d * SCAN_BLOCKS + t] : 0;
  s[t] = v;
  __syncthreads();
  for (int off = 1; off < 128; off <<= 1) {
    int add = (t >= off) ? s[t - off] : 0;
    __syncthreads();
    s[t] += add;
    __syncthreads();
  }
  if (t < SCAN_BLOCKS) chunk_off[d * SCAN_BLOCKS + t] = s[t] - v;
  if (t == 127) rp[d * (N_NODES + 1) + N_NODES] = s[127];
}

__global__ void scanC_kernel(const int* __restrict__ tmp,
                             const int* __restrict__ chunk_off,
                             int* __restrict__ rp, int* __restrict__ cursor) {
  int d = blockIdx.y;
  int i = blockIdx.x * SCAN_CHUNK + threadIdx.x;
  if (i < N_NODES) {
    int v = tmp[d * N_NODES + i] + chunk_off[d * SCAN_BLOCKS + blockIdx.x];
    rp[d * (N_NODES + 1) + i] = v;
    cursor[d * N_NODES + i] = v;
  }
}

// rel-scatter producing perm, per-slot SOURCE node ids (srcf/srcr), AND the
// dst-keyed col lists in one pass
__global__ void scatter_all_kernel(const int* __restrict__ rel,
                                   const int* __restrict__ dep,
                                   const int* __restrict__ gov,
                                   const int* __restrict__ block_offset,
                                   int* __restrict__ cursor,
                                   int* __restrict__ perm,
                                   int* __restrict__ srcf,
                                   int* __restrict__ srcr,
                                   int* __restrict__ colf,
                                   int* __restrict__ colr) {
  __shared__ int cur[N_REL];
  if (threadIdx.x < N_REL)
    cur[threadIdx.x] = block_offset[blockIdx.x * N_REL + threadIdx.x];
  __syncthreads();
  int beg = blockIdx.x * SORT_CHUNK;
  int end = min(beg + SORT_CHUNK, N_EDGES);
  for (int e = beg + threadIdx.x; e < end; e += blockDim.x) {
    int dp = dep[e], gv = gov[e];
    int pos = atomicAdd(&cur[rel[e]], 1);  // LDS atomic, cheap
    perm[pos] = e;
    srcf[pos] = gv;   // fwd msg source = governor
    srcr[pos] = dp;   // rev msg source = dependent
    colf[atomicAdd(&cursor[dp], 1)] = pos;             // fwd msg pos -> dep
    colr[atomicAdd(&cursor[N_NODES + gv], 1)] = pos;   // rev msg pos -> gov
  }
}

// ---- mega GEMM: buckets 0..9 fwd-edge, 10..19 rev-edge, 20/21 self -------
// Edge buckets write bf16 msg rows (linear slots) in C/D-permuted column
// order: short at row*DIM + nb + lm*4 + i holds col nb + i*16 + lm.
// Self buckets (split for load balance) write fp32 directly to out.
//
// Staging: global_load_lds (width 16) into a DOUBLE-BUFFERED linear LDS
// tile (zero VGPR cost — the round-1 reg-staged prefetch spilled d[8] to
// scratch: +165 MB HBM writes). Bank conflicts handled by T2 both-sides
// XOR swizzle: LDS dest linear, global source chunk pre-swizzled by
// (row&7), ds_read applies the same XOR. One __syncthreads per tile; its
// vmcnt(0) drain is the readiness guarantee for the in-flight buffer.
// Buffer parity unrolled 2x with literal indices (no dynamic-indexed regs).

__global__ __launch_bounds__(256, 2)
void mega_gemm_kernel(const unsigned short* __restrict__ xbf,
                      const unsigned short* __restrict__ wt,
                      const float* __restrict__ b_self,
                      const float* __restrict__ b_fwd,
                      const float* __restrict__ b_rev,
                      const int* __restrict__ srcf,
                      const int* __restrict__ srcr,
                      const int* __restrict__ rel_start,
                      unsigned short* __restrict__ msg,
                      float* __restrict__ out) {
  const int bkt = blockIdx.y;
  const bool is_self = (bkt >= 2 * N_REL);
  const bool fwd = bkt < N_REL;
  const int r = is_self ? 0 : (fwd ? bkt : bkt - N_REL);

  int beg, cnt;
  const int* src_arr = fwd ? srcf : srcr;
  unsigned short* mdir = msg + (fwd ? 0 : (size_t)N_EDGES * DIM);
  if (is_self) {
    beg = (bkt - 2 * N_REL) * (N_NODES / 2);  // 0 or 15000
    cnt = N_NODES / 2;
  } else {
    beg = rel_start[r];
    cnt = rel_start[r + 1] - beg;
  }
  const int ntiles = (cnt + 63) >> 6;
  const int GX = gridDim.x;

  const int tid = threadIdx.x;
  const int wave = tid >> 6, lane = tid & 63;
  const int lm = lane & 15, q = lane >> 4;
  const int nb = wave * 64;
  const int half = lane >> 5;      // 0 or 1

  __shared__ int s_src[2][64];
  __shared__ unsigned short sA[2][64 * DIM];  // 2 x 32 KB, linear rows

  // hoisted, tile-invariant W fragments (128 VGPRs)
  bf16x8 wf[8][4];
  const unsigned short* wbase =
      wt + (size_t)(is_self ? 2 * N_REL : bkt) * DIM * DIM;
  #pragma unroll
  for (int kk = 0; kk < 8; ++kk)
    #pragma unroll
    for (int ni = 0; ni < 4; ++ni)
      wf[kk][ni] = *reinterpret_cast<const bf16x8*>(
          wbase + (size_t)(nb + ni * 16 + lm) * DIM + kk * 32 + q * 8);

  const float* bptr = is_self ? b_self : ((fwd ? b_fwd : b_rev) + r * DIM);
  float bias[4];
  #pragma unroll
  for (int ni = 0; ni < 4; ++ni) bias[ni] = bptr[nb + ni * 16 + lm];

  // lane-constant address pieces (all compile-time-indexed; stay in regs)
  int swz[8];     // staging: global chunk offset (shorts) for gll instr i
  #pragma unroll
  for (int i = 0; i < 8; ++i)
    swz[i] = (((lane & 31) ^ ((i * 2 + half) & 7)) * 8);
  int rowoff[4];  // ds_read: row byte base (in shorts)
  #pragma unroll
  for (int mi = 0; mi < 4; ++mi) rowoff[mi] = (mi * 16 + lm) * DIM;
  int ckoff[8];   // ds_read: swizzled chunk offset (shorts)
  #pragma unroll
  for (int kk = 0; kk < 8; ++kk)
    ckoff[kk] = ((kk * 4 + q) ^ (lm & 7)) * 8;

  int t = blockIdx.x;
  if (t >= ntiles) return;  // uniform over block: safe w.r.t. barriers

  // idx fetch for tile tt (tid<64 lanes only)
  auto load_idx = [&](int tt) -> int {
    int tile0_ = tt << 6;
    if (is_self) {
      int rr = beg + tile0_ + tid;
      return rr < beg + cnt ? rr : beg + cnt - 1;
    } else {
      int p_ = tile0_ + tid;
      p_ = p_ < cnt ? p_ : cnt - 1;
      return src_arr[beg + p_];
    }
  };

  // issue the 64-row gather for buffer p via global_load_lds (linear dest,
  // pre-swizzled source). 8 instrs/wave, 2 rows each (lanes 0-31 / 32-63).
  auto issue_stage = [&](int p) {
    const int* sp = s_src[p];
    unsigned short* db = sA[p];
    #pragma unroll
    for (int i = 0; i < 8; ++i) {
      int ldsrow = wave * 16 + i * 2;
      int rr = sp[ldsrow + half];
      const unsigned short* g = xbf + (size_t)rr * DIM + swz[i];
      __builtin_amdgcn_global_load_lds(
          (const __attribute__((address_space(1))) void*)g,
          (__attribute__((address_space(3))) void*)(db + ldsrow * DIM),
          16, 0, 0);
    }
  };

  // one pipelined tile at parity cur (literal 0/1 at both call sites)
  auto step = [&](int cur) {
    const int tile0 = t << 6;
    const int rows_valid = min(64, cnt - tile0);
    const bool have_next = (t + GX) < ntiles;
    const bool have_next2 = (t + 2 * GX) < ntiles;

    __syncthreads();  // drains vmcnt: sA[cur] ready; s_src[cur^1] visible
    if (have_next) issue_stage(cur ^ 1);              // flies under compute
    if (tid < 64 && have_next2) s_src[cur][tid] = load_idx(t + 2 * GX);

    f32x4 acc[4][4];
    #pragma unroll
    for (int mi = 0; mi < 4; ++mi)
      #pragma unroll
      for (int ni = 0; ni < 4; ++ni)
        acc[mi][ni] = (f32x4){0.f, 0.f, 0.f, 0.f};

    const unsigned short* sAb = sA[cur];
    #pragma unroll
    for (int kk = 0; kk < 8; ++kk) {
      bf16x8 a[4];
      #pragma unroll
      for (int mi = 0; mi < 4; ++mi)
        a[mi] = *reinterpret_cast<const bf16x8*>(sAb + rowoff[mi] + ckoff[kk]);
      #pragma unroll
      for (int mi = 0; mi < 4; ++mi)
        #pragma unroll
        for (int ni = 0; ni < 4; ++ni)
          acc[mi][ni] = __builtin_amdgcn_mfma_f32_16x16x32_bf16(
              a[mi], wf[kk][ni], acc[mi][ni], 0, 0, 0);
    }

    if (is_self) {
      // direct fp32 stores to out (C/D layout; row = quad*4 + reg)
      #pragma unroll
      for (int mi = 0; mi < 4; ++mi) {
        #pragma unroll
        for (int reg = 0; reg < 4; ++reg) {
          int row = mi * 16 + q * 4 + reg;
          if (row < rows_valid) {
            #pragma unroll
            for (int ni = 0; ni < 4; ++ni)
              out[(size_t)(beg + tile0 + row) * DIM + nb + ni * 16 + lm] =
                  acc[mi][ni][reg] + bias[ni];
          }
        }
      }
    } else {
      // permuted uint2 bf16 stores to linear msg slots
      #pragma unroll
      for (int mi = 0; mi < 4; ++mi) {
        #pragma unroll
        for (int reg = 0; reg < 4; ++reg) {
          int row = mi * 16 + q * 4 + reg;
          if (row < rows_valid) {
            unsigned int p0 = ((unsigned int)f2bf(acc[mi][1][reg] + bias[1]) << 16) |
                              f2bf(acc[mi][0][reg] + bias[0]);
            unsigned int p1 = ((unsigned int)f2bf(acc[mi][3][reg] + bias[3]) << 16) |
                              f2bf(acc[mi][2][reg] + bias[2]);
            uint2 u; u.x = p0; u.y = p1;
            *reinterpret_cast<uint2*>(
                mdir + (size_t)(beg + tile0 + row) * DIM + nb + lm * 4) = u;
          }
        }
      }
    }
  };

  // ---- pipeline prologue -------------------------------------------------
  if (tid < 64) s_src[0][tid] = load_idx(t);
  __syncthreads();
  issue_stage(0);
  if (tid < 64 && t + GX < ntiles) s_src[1][tid] = load_idx(t + GX);

  // ---- main loop, parity unrolled ---------------------------------------
  while (true) {
    step(0);
    t += GX; if (t >= ntiles) break;
    step(1);
    t += GX; if (t >= ntiles) break;
  }
}

// ---- phase 2: CSR gather-sum, 4-row parallel, uint2 loads, permuted cols -

__global__ void reduce_both_kernel(const unsigned short* __restrict__ msg,
                                   const int* __restrict__ rp,
                                   const int* __restrict__ colf,
                                   const int* __restrict__ colr,
                                   float* __restrict__ out) {
  const int n = blockIdx.x, t = threadIdx.x;
  const int g = t >> 6, lane = t & 63;
  const int b0 = rp[n], e0 = rp[n + 1];
  const int b1 = rp[(N_NODES + 1) + n], e1 = rp[(N_NODES + 1) + n + 1];
  if (e0 <= b0 && e1 <= b1) return;

  float a0 = 0.f, a1 = 0.f, a2 = 0.f, a3 = 0.f;
  for (int j = b0 + g; j < e0; j += 4) {
    int row = colf[j];
    uint2 v = *reinterpret_cast<const uint2*>(msg + (size_t)row * DIM + lane * 4);
    union { unsigned int u; float f; } c;
    c.u = v.x << 16;          a0 += c.f;
    c.u = v.x & 0xffff0000u;  a1 += c.f;
    c.u = v.y << 16;          a2 += c.f;
    c.u = v.y & 0xffff0000u;  a3 += c.f;
  }
  for (int j = b1 + g; j < e1; j += 4) {
    int row = colr[j];
    uint2 v = *reinterpret_cast<const uint2*>(
        msg + (size_t)(N_EDGES + row) * DIM + lane * 4);
    union { unsigned int u; float f; } c;
    c.u = v.x << 16;          a0 += c.f;
    c.u = v.x & 0xffff0000u;  a1 += c.f;
    c.u = v.y << 16;          a2 += c.f;
    c.u = v.y & 0xffff0000u;  a3 += c.f;
  }

  // invert the storage permutation: short i of thread's uint2 is column
  // (lane>>4)*64 + i*16 + (lane&15)
  __shared__ float part[4][DIM];
  const int cb = (lane >> 4) * 64 + (lane & 15);
  part[g][cb +  0] = a0;
  part[g][cb + 16] = a1;
  part[g][cb + 32] = a2;
  part[g][cb + 48] = a3;
  __syncthreads();
  float s = part[0][t] + part[1][t] + part[2][t] + part[3][t];
  out[(size_t)n * DIM + t] += s;
}

// ---- fallback: single-phase atomic scatter (if ws too small) -------------

__global__ __launch_bounds__(256, 2)
void self_gemm_kernel(const unsigned short* __restrict__ xbf,
                      const unsigned short* __restrict__ wt_self,
                      const float* __restrict__ b_self,
                      float* __restrict__ out) {
  const int tid = threadIdx.x;
  const int wave = tid >> 6, lane = tid & 63;
  const int lm = lane & 15, q = lane >> 4;
  const int nb = wave * 64;

  bf16x8 wf[8][4];
  #pragma unroll
  for (int kk = 0; kk < 8; ++kk)
    #pragma unroll
    for (int ni = 0; ni < 4; ++ni)
      wf[kk][ni] = *reinterpret_cast<const bf16x8*>(
          wt_self + (size_t)(nb + ni * 16 + lm) * DIM + kk * 32 + q * 8);

  float bias[4];
  #pragma unroll
  for (int ni = 0; ni < 4; ++ni) bias[ni] = b_self[nb + ni * 16 + lm];

  const int ntiles = (N_NODES + 63) / 64;
  for (int t = blockIdx.x; t < ntiles; t += gridDim.x) {
    const int row0 = t * 64;
    const unsigned short* xr[4];
    #pragma unroll
    for (int mi = 0; mi < 4; ++mi) {
      int r = row0 + mi * 16 + lm;
      int rc = r < N_NODES ? r : N_NODES - 1;
      xr[mi] = xbf + (size_t)rc * DIM + q * 8;
    }

    f32x4 acc[4][4];
    #pragma unroll
    for (int mi = 0; mi < 4; ++mi)
      #pragma unroll
      for (int ni = 0; ni < 4; ++ni)
        acc[mi][ni] = (f32x4){0.f, 0.f, 0.f, 0.f};

    #pragma unroll
    for (int kk = 0; kk < 8; ++kk) {
      bf16x8 a[4];
      #pragma unroll
      for (int mi = 0; mi < 4; ++mi)
        a[mi] = *reinterpret_cast<const bf16x8*>(xr[mi] + kk * 32);
      #pragma unroll
      for (int mi = 0; mi < 4; ++mi)
        #pragma unroll
        for (int ni = 0; ni < 4; ++ni)
          acc[mi][ni] = __builtin_amdgcn_mfma_f32_16x16x32_bf16(a[mi], wf[kk][ni], acc[mi][ni], 0, 0, 0);
    }

    #pragma unroll
    for (int mi = 0; mi < 4; ++mi) {
      #pragma unroll
      for (int reg = 0; reg < 4; ++reg) {
        int row = row0 + mi * 16 + q * 4 + reg;
        if (row < N_NODES) {
          #pragma unroll
          for (int ni = 0; ni < 4; ++ni)
            out[(size_t)row * DIM + nb + ni * 16 + lm] = acc[mi][ni][reg] + bias[ni];
        }
      }
    }
  }
}

__global__ void edge_gemm_atomic_kernel(const unsigned short* __restrict__ xbf,
                                        const unsigned short* __restrict__ wt,
                                        const float* __restrict__ b_fwd,
                                        const float* __restrict__ b_rev,
                                        const int* __restrict__ perm,
                                        const int* __restrict__ rel_start,
                                        const int* __restrict__ dep,
                                        const int* __restrict__ gov,
                                        float* __restrict__ out) {
  const int bucket = blockIdx.y;
  const int r = bucket % N_REL;
  const bool fwd = bucket < N_REL;
  const int beg = rel_start[r];
  const int cnt = rel_start[r + 1] - beg;
  const int ntiles = (cnt + 63) >> 6;

  const int tid = threadIdx.x;
  const int wave = tid >> 6, lane = tid & 63;
  const int lm = lane & 15, q = lane >> 4;
  const int nb = wave * 64;

  __shared__ int s_src[64], s_dst[64];

  const unsigned short* wr[4];
  #pragma unroll
  for (int ni = 0; ni < 4; ++ni)
    wr[ni] = wt + (size_t)bucket * DIM * DIM + (size_t)(nb + ni * 16 + lm) * DIM + q * 8;

  const float* bptr = (fwd ? b_fwd : b_rev) + r * DIM;
  float bias[4];
  #pragma unroll
  for (int ni = 0; ni < 4; ++ni) bias[ni] = bptr[nb + ni * 16 + lm];

  for (int t = blockIdx.x; t < ntiles; t += gridDim.x) {
    const int tile0 = t << 6;
    const int rows_valid = min(64, cnt - tile0);

    if (tid < 64) {
      int s = 0, d = -1;
      if (tid < rows_valid) {
        int e = perm[beg + tile0 + tid];
        int gv = gov[e], dp = dep[e];
        s = fwd ? gv : dp;
        d = fwd ? dp : gv;
      }
      s_src[tid] = s;
      s_dst[tid] = d;
    }
    __syncthreads();

    const unsigned short* xr[4];
    #pragma unroll
    for (int mi = 0; mi < 4; ++mi)
      xr[mi] = xbf + (size_t)s_src[mi * 16 + lm] * DIM + q * 8;

    f32x4 acc[4][4];
    #pragma unroll
    for (int mi = 0; mi < 4; ++mi)
      #pragma unroll
      for (int ni = 0; ni < 4; ++ni)
        acc[mi][ni] = (f32x4){0.f, 0.f, 0.f, 0.f};

    #pragma unroll
    for (int k0 = 0; k0 < DIM; k0 += 32) {
      bf16x8 a[4], b[4];
      #pragma unroll
      for (int mi = 0; mi < 4; ++mi) a[mi] = *reinterpret_cast<const bf16x8*>(xr[mi] + k0);
      #pragma unroll
      for (int ni = 0; ni < 4; ++ni) b[ni] = *reinterpret_cast<const bf16x8*>(wr[ni] + k0);
      #pragma unroll
      for (int mi = 0; mi < 4; ++mi)
        #pragma unroll
        for (int ni = 0; ni < 4; ++ni)
          acc[mi][ni] = __builtin_amdgcn_mfma_f32_16x16x32_bf16(a[mi], b[ni], acc[mi][ni], 0, 0, 0);
    }

    #pragma unroll
    for (int mi = 0; mi < 4; ++mi) {
      #pragma unroll
      for (int reg = 0; reg < 4; ++reg) {
        int row = mi * 16 + q * 4 + reg;
        if (row < rows_valid) {
          int dst = s_dst[row];
          float* op = out + (size_t)dst * DIM + nb + lm;
          #pragma unroll
          for (int ni = 0; ni < 4; ++ni)
            atomicAdd(op + ni * 16, acc[mi][ni][reg] + bias[ni]);
        }
      }
    }
    __syncthreads();
  }
}

// ---- launch --------------------------------------------------------------

extern "C" void kernel_launch(void* const* d_in, const int* in_sizes, int n_in,
                              void* d_out, int out_size, void* d_ws, size_t ws_size,
                              hipStream_t stream) {
  const float* x      = (const float*)d_in[0];
  const float* W_self = (const float*)d_in[1];
  const float* b_self = (const float*)d_in[2];
  const float* W_fwd  = (const float*)d_in[3];
  const float* b_fwd  = (const float*)d_in[4];
  const float* W_rev  = (const float*)d_in[5];
  const float* b_rev  = (const float*)d_in[6];
  const int* dep = (const int*)d_in[7];
  const int* rel = (const int*)d_in[8];
  const int* gov = (const int*)d_in[9];
  float* out = (float*)d_out;

  char* base = (char*)d_ws;
  size_t off = 0;
  auto alloc = [&](size_t bytes) -> char* {
    char* p = base + off;
    off = (off + bytes + 15) & ~(size_t)15;
    return p;
  };

  unsigned short* xbf = (unsigned short*)alloc((size_t)N_NODES * DIM * 2);   // 15.36 MB
  unsigned short* wt  = (unsigned short*)alloc((size_t)21 * DIM * DIM * 2);  // 2.75 MB
  int* perm          = (int*)alloc((size_t)N_EDGES * 4);
  int* srcf          = (int*)alloc((size_t)N_EDGES * 4);
  int* srcr          = (int*)alloc((size_t)N_EDGES * 4);
  int* rel_start     = (int*)alloc(16 * 4);
  int* block_counts  = (int*)alloc(SORT_BLOCKS * N_REL * 4);
  int* block_offset  = (int*)alloc(SORT_BLOCKS * N_REL * 4);
  int* cnt       = (int*)alloc((size_t)2 * N_NODES * 4);
  int* tmp       = (int*)alloc((size_t)2 * N_NODES * 4);
  int* sums      = (int*)alloc((size_t)2 * SCAN_BLOCKS * 4);
  int* chunk_off = (int*)alloc((size_t)2 * SCAN_BLOCKS * 4);
  int* rp        = (int*)alloc((size_t)2 * (N_NODES + 1) * 4);
  int* cursor    = (int*)alloc((size_t)2 * N_NODES * 4);
  int* colf      = (int*)alloc((size_t)N_EDGES * 4);
  int* colr      = (int*)alloc((size_t)N_EDGES * 4);
  unsigned short* msg = (unsigned short*)alloc((size_t)2 * N_EDGES * DIM * 2);  // 153.6 MB
  const bool two_phase = (off <= ws_size);

  prep_kernel<<<PREP_XB + PREP_WB + PREP_ZB, 256, 0, stream>>>(
      x, W_fwd, W_rev, W_self, xbf, wt, cnt);
  hist_all_kernel<<<SORT_BLOCKS, 256, 0, stream>>>(rel, dep, gov, block_counts, cnt);
  scan_rel_kernel<<<1, 64, 0, stream>>>(block_counts, rel_start, block_offset);
  scanA_kernel<<<dim3(SCAN_BLOCKS, 2), SCAN_CHUNK, 0, stream>>>(cnt, tmp, sums);
  scanB_kernel<<<2, 128, 0, stream>>>(sums, chunk_off, rp);
  scanC_kernel<<<dim3(SCAN_BLOCKS, 2), SCAN_CHUNK, 0, stream>>>(tmp, chunk_off, rp, cursor);
  scatter_all_kernel<<<SORT_BLOCKS, 256, 0, stream>>>(
      rel, dep, gov, block_offset, cursor, perm, srcf, srcr, colf, colr);

  if (two_phase) {
    // buckets 0..19 edges -> msg; buckets 20/21 self halves -> out
    mega_gemm_kernel<<<dim3(48, 2 * N_REL + 2), 256, 0, stream>>>(
        xbf, wt, b_self, b_fwd, b_rev, srcf, srcr, rel_start, msg, out);
    reduce_both_kernel<<<N_NODES, 256, 0, stream>>>(msg, rp, colf, colr, out);
  } else {
    self_gemm_kernel<<<120, 256, 0, stream>>>(
        xbf, wt + (size_t)20 * DIM * DIM, b_self, out);
    edge_gemm_atomic_kernel<<<dim3(260, 20), 256, 0, stream>>>(
        xbf, wt, b_fwd, b_rev, perm, rel_start, dep, gov, out);
  }
}

// Round 3
// 265.809 us; speedup vs baseline: 1.2176x; 1.0846x over previous
//
#include <hip/hip_runtime.h>

#define N_NODES 30000
#define N_EDGES 150000
#define N_REL 10
#define DIM 256

#define SORT_BLOCKS 120
#define SORT_CHUNK ((N_EDGES + SORT_BLOCKS - 1) / SORT_BLOCKS)  // 1250

#define SCAN_CHUNK 256
#define SCAN_BLOCKS ((N_NODES + SCAN_CHUNK - 1) / SCAN_CHUNK)   // 118

// prep kernel block ranges (hist fused in; cnt zeroed by hipMemsetAsync)
#define PREP_XB 7500   // conv_x: 30000*256/4/256
#define PREP_WB 5376   // conv_w: 21*65536/256

typedef __attribute__((ext_vector_type(8))) short bf16x8;
typedef __attribute__((ext_vector_type(4))) float f32x4;

__device__ __forceinline__ unsigned short f2bf(float f) {
  union { float f; unsigned int u; } v; v.f = f;
  unsigned int u = v.u;
  unsigned int r = u + 0x7fffu + ((u >> 16) & 1u);  // RNE
  return (unsigned short)(r >> 16);
}

// ---- K1: fused x->bf16, W->bf16 transposed, edge histograms --------------

__global__ void prep_hist_kernel(const float* __restrict__ x,
                                 const float* __restrict__ Wf,
                                 const float* __restrict__ Wr,
                                 const float* __restrict__ Ws,
                                 const int* __restrict__ rel,
                                 const int* __restrict__ dep,
                                 const int* __restrict__ gov,
                                 unsigned short* __restrict__ xbf,
                                 unsigned short* __restrict__ wt,
                                 int* __restrict__ block_counts,
                                 int* __restrict__ cnt) {
  int b = blockIdx.x;
  if (b < PREP_XB) {
    int idx = b * 256 + threadIdx.x;  // one float4 each, exact
    float4 v = reinterpret_cast<const float4*>(x)[idx];
    ushort4 o;
    o.x = f2bf(v.x); o.y = f2bf(v.y); o.z = f2bf(v.z); o.w = f2bf(v.w);
    reinterpret_cast<ushort4*>(xbf)[idx] = o;
  } else if (b < PREP_XB + PREP_WB) {
    int idx = (b - PREP_XB) * 256 + threadIdx.x;  // wt[b][o][i] = W_b[i][o]
    int bb = idx >> 16;
    int t = idx & 65535;
    int o = t >> 8, i = t & 255;
    const float* src = (bb < N_REL) ? (Wf + (size_t)bb * 65536)
                     : (bb < 2 * N_REL) ? (Wr + (size_t)(bb - N_REL) * 65536)
                     : Ws;
    wt[idx] = f2bf(src[i * 256 + o]);
  } else {
    // hist blocks: per-block rel histogram (LDS) + global dst histograms
    int hb = b - PREP_XB - PREP_WB;
    __shared__ int h[N_REL];
    if (threadIdx.x < N_REL) h[threadIdx.x] = 0;
    __syncthreads();
    int beg = hb * SORT_CHUNK;
    int end = min(beg + SORT_CHUNK, N_EDGES);
    for (int e = beg + threadIdx.x; e < end; e += blockDim.x) {
      atomicAdd(&h[rel[e]], 1);
      atomicAdd(&cnt[dep[e]], 1);             // 30k bins: low contention
      atomicAdd(&cnt[N_NODES + gov[e]], 1);
    }
    __syncthreads();
    if (threadIdx.x < N_REL)
      block_counts[hb * N_REL + threadIdx.x] = h[threadIdx.x];
  }
}

// ---- K2: per-chunk inclusive scan of cnt ---------------------------------

__global__ void scanA_kernel(const int* __restrict__ cnt,
                             int* __restrict__ tmp, int* __restrict__ sums) {
  __shared__ int s[SCAN_CHUNK];
  int d = blockIdx.y, b = blockIdx.x, t = threadIdx.x;
  int i = b * SCAN_CHUNK + t;
  int v = (i < N_NODES) ? cnt[d * N_NODES + i] : 0;
  s[t] = v;
  __syncthreads();
  for (int off = 1; off < SCAN_CHUNK; off <<= 1) {
    int add = (t >= off) ? s[t - off] : 0;
    __syncthreads();
    s[t] += add;
    __syncthreads();
  }
  if (i < N_NODES) tmp[d * N_NODES + i] = s[t] - v;  // exclusive
  if (t == SCAN_CHUNK - 1) sums[d * SCAN_BLOCKS + b] = s[t];
}

// ---- K3: finish scan (each block redundantly scans the 118 chunk sums);
//          block x==SCAN_BLOCKS (y==0) does the rel scan ------------------

__global__ void scan_finish_kernel(const int* __restrict__ sums,
                                   const int* __restrict__ tmp,
                                   const int* __restrict__ block_counts,
                                   int* __restrict__ rp,
                                   int* __restrict__ cursor,
                                   int* __restrict__ rel_start,
                                   int* __restrict__ block_offset) {
  int d = blockIdx.y, b = blockIdx.x, t = threadIdx.x;

  if (b == SCAN_BLOCKS) {
    if (d == 1) return;
    __shared__ int tot[N_REL];
    __shared__ int rstart[N_REL + 1];
    int r = t;
    if (r < N_REL) {
      int s = 0;
      for (int bb = 0; bb < SORT_BLOCKS; ++bb) s += block_counts[bb * N_REL + r];
      tot[r] = s;
    }
    __syncthreads();
    if (t == 0) {
      int s = 0;
      for (int i = 0; i < N_REL; ++i) { rstart[i] = s; s += tot[i]; }
      rstart[N_REL] = s;
      for (int i = 0; i <= N_REL; ++i) rel_start[i] = rstart[i];
    }
    __syncthreads();
    if (r < N_REL) {
      int run = rstart[r];
      for (int bb = 0; bb < SORT_BLOCKS; ++bb) {
        block_offset[bb * N_REL + r] = run;
        run += block_counts[bb * N_REL + r];
      }
    }
    return;
  }

  __shared__ int ssum[SCAN_BLOCKS];
  __shared__ int spre[SCAN_BLOCKS + 1];
  if (t < SCAN_BLOCKS) ssum[t] = sums[d * SCAN_BLOCKS + t];
  __syncthreads();
  if (t == 0) {
    int run = 0;
    for (int i = 0; i < SCAN_BLOCKS; ++i) { spre[i] = run; run += ssum[i]; }
    spre[SCAN_BLOCKS] = run;
  }
  __syncthreads();
  int chunk = spre[b];
  int i = b * SCAN_CHUNK + t;
  if (i < N_NODES) {
    int v = tmp[d * N_NODES + i] + chunk;
    rp[d * (N_NODES + 1) + i] = v;
    cursor[d * N_NODES + i] = v;
  }
  if (b == 0 && t == 0) rp[d * (N_NODES + 1) + N_NODES] = spre[SCAN_BLOCKS];
}

// ---- K4: rel-scatter producing perm, per-slot src ids, dst col lists -----

__global__ void scatter_all_kernel(const int* __restrict__ rel,
                                   const int* __restrict__ dep,
                                   const int* __restrict__ gov,
                                   const int* __restrict__ block_offset,
                                   int* __restrict__ cursor,
                                   int* __restrict__ perm,
                                   int* __restrict__ srcf,
                                   int* __restrict__ srcr,
                                   int* __restrict__ colf,
                                   int* __restrict__ colr) {
  __shared__ int cur[N_REL];
  if (threadIdx.x < N_REL)
    cur[threadIdx.x] = block_offset[blockIdx.x * N_REL + threadIdx.x];
  __syncthreads();
  int beg = blockIdx.x * SORT_CHUNK;
  int end = min(beg + SORT_CHUNK, N_EDGES);
  for (int e = beg + threadIdx.x; e < end; e += blockDim.x) {
    int dp = dep[e], gv = gov[e];
    int pos = atomicAdd(&cur[rel[e]], 1);  // LDS atomic, cheap
    perm[pos] = e;
    srcf[pos] = gv;   // fwd msg source = governor
    srcr[pos] = dp;   // rev msg source = dependent
    colf[atomicAdd(&cursor[dp], 1)] = pos;             // fwd msg pos -> dep
    colr[atomicAdd(&cursor[N_NODES + gv], 1)] = pos;   // rev msg pos -> gov
  }
}

// ---- K5 mega GEMM: buckets 0..9 fwd-edge, 10..19 rev-edge, 20/21 self ----
// Staging: global_load_lds (w16) into double-buffered linear LDS, T2
// both-sides XOR swizzle (linear dest, pre-swizzled source, swizzled read).
// Inner loop is mi-OUTER: each 16-row output block's stores issue right
// after its own MFMAs, hiding store latency under the next block's MFMAs;
// only mi=3's stores sit exposed at the tile barrier.

__global__ __launch_bounds__(256, 2)
void mega_gemm_kernel(const unsigned short* __restrict__ xbf,
                      const unsigned short* __restrict__ wt,
                      const float* __restrict__ b_self,
                      const float* __restrict__ b_fwd,
                      const float* __restrict__ b_rev,
                      const int* __restrict__ srcf,
                      const int* __restrict__ srcr,
                      const int* __restrict__ rel_start,
                      unsigned short* __restrict__ msg,
                      float* __restrict__ out) {
  const int bkt = blockIdx.y;
  const bool is_self = (bkt >= 2 * N_REL);
  const bool fwd = bkt < N_REL;
  const int r = is_self ? 0 : (fwd ? bkt : bkt - N_REL);

  int beg, cnt;
  const int* src_arr = fwd ? srcf : srcr;
  unsigned short* mdir = msg + (fwd ? 0 : (size_t)N_EDGES * DIM);
  if (is_self) {
    beg = (bkt - 2 * N_REL) * (N_NODES / 2);  // 0 or 15000
    cnt = N_NODES / 2;
  } else {
    beg = rel_start[r];
    cnt = rel_start[r + 1] - beg;
  }
  const int ntiles = (cnt + 63) >> 6;
  const int GX = gridDim.x;

  const int tid = threadIdx.x;
  const int wave = tid >> 6, lane = tid & 63;
  const int lm = lane & 15, q = lane >> 4;
  const int nb = wave * 64;
  const int half = lane >> 5;      // 0 or 1

  __shared__ int s_src[2][64];
  __shared__ unsigned short sA[2][64 * DIM];  // 2 x 32 KB, linear rows

  // hoisted, tile-invariant W fragments (128 VGPRs)
  bf16x8 wf[8][4];
  const unsigned short* wbase =
      wt + (size_t)(is_self ? 2 * N_REL : bkt) * DIM * DIM;
  #pragma unroll
  for (int kk = 0; kk < 8; ++kk)
    #pragma unroll
    for (int ni = 0; ni < 4; ++ni)
      wf[kk][ni] = *reinterpret_cast<const bf16x8*>(
          wbase + (size_t)(nb + ni * 16 + lm) * DIM + kk * 32 + q * 8);

  const float* bptr = is_self ? b_self : ((fwd ? b_fwd : b_rev) + r * DIM);
  float bias[4];
  #pragma unroll
  for (int ni = 0; ni < 4; ++ni) bias[ni] = bptr[nb + ni * 16 + lm];

  // lane-constant address pieces (all compile-time-indexed; stay in regs)
  int swz[8];     // staging: global chunk offset (shorts) for gll instr i
  #pragma unroll
  for (int i = 0; i < 8; ++i)
    swz[i] = (((lane & 31) ^ ((i * 2 + half) & 7)) * 8);
  int rowoff[4];  // ds_read: row base (in shorts)
  #pragma unroll
  for (int mi = 0; mi < 4; ++mi) rowoff[mi] = (mi * 16 + lm) * DIM;
  int ckoff[8];   // ds_read: swizzled chunk offset (shorts)
  #pragma unroll
  for (int kk = 0; kk < 8; ++kk)
    ckoff[kk] = ((kk * 4 + q) ^ (lm & 7)) * 8;

  int t = blockIdx.x;
  if (t >= ntiles) return;  // uniform over block: safe w.r.t. barriers

  // idx fetch for tile tt (tid<64 lanes only)
  auto load_idx = [&](int tt) -> int {
    int tile0_ = tt << 6;
    if (is_self) {
      int rr = beg + tile0_ + tid;
      return rr < beg + cnt ? rr : beg + cnt - 1;
    } else {
      int p_ = tile0_ + tid;
      p_ = p_ < cnt ? p_ : cnt - 1;
      return src_arr[beg + p_];
    }
  };

  // issue the 64-row gather for buffer p via global_load_lds (linear dest,
  // pre-swizzled source). 8 instrs/wave, 2 rows each (lanes 0-31 / 32-63).
  auto issue_stage = [&](int p) {
    const int* sp = s_src[p];
    unsigned short* db = sA[p];
    #pragma unroll
    for (int i = 0; i < 8; ++i) {
      int ldsrow = wave * 16 + i * 2;
      int rr = sp[ldsrow + half];
      const unsigned short* g = xbf + (size_t)rr * DIM + swz[i];
      __builtin_amdgcn_global_load_lds(
          (const __attribute__((address_space(1))) void*)g,
          (__attribute__((address_space(3))) void*)(db + ldsrow * DIM),
          16, 0, 0);
    }
  };

  // one pipelined tile at parity cur (literal 0/1 at both call sites)
  auto step = [&](int cur) {
    const int tile0 = t << 6;
    const int rows_valid = min(64, cnt - tile0);
    const bool have_next = (t + GX) < ntiles;
    const bool have_next2 = (t + 2 * GX) < ntiles;

    __syncthreads();  // drains vmcnt: sA[cur] ready; s_src[cur^1] visible
    if (have_next) issue_stage(cur ^ 1);              // flies under compute
    if (tid < 64 && have_next2) s_src[cur][tid] = load_idx(t + 2 * GX);

    const unsigned short* sAb = sA[cur];
    #pragma unroll
    for (int mi = 0; mi < 4; ++mi) {
      bf16x8 a[8];
      #pragma unroll
      for (int kk = 0; kk < 8; ++kk)
        a[kk] = *reinterpret_cast<const bf16x8*>(sAb + rowoff[mi] + ckoff[kk]);

      f32x4 acc[4];
      #pragma unroll
      for (int ni = 0; ni < 4; ++ni) acc[ni] = (f32x4){0.f, 0.f, 0.f, 0.f};

      __builtin_amdgcn_s_setprio(1);
      #pragma unroll
      for (int kk = 0; kk < 8; ++kk)
        #pragma unroll
        for (int ni = 0; ni < 4; ++ni)
          acc[ni] = __builtin_amdgcn_mfma_f32_16x16x32_bf16(
              a[kk], wf[kk][ni], acc[ni], 0, 0, 0);
      __builtin_amdgcn_s_setprio(0);

      if (is_self) {
        // direct fp32 stores to out (C/D layout; row = quad*4 + reg)
        #pragma unroll
        for (int reg = 0; reg < 4; ++reg) {
          int row = mi * 16 + q * 4 + reg;
          if (row < rows_valid) {
            #pragma unroll
            for (int ni = 0; ni < 4; ++ni)
              out[(size_t)(beg + tile0 + row) * DIM + nb + ni * 16 + lm] =
                  acc[ni][reg] + bias[ni];
          }
        }
      } else {
        // permuted uint2 bf16 stores to linear msg slots
        #pragma unroll
        for (int reg = 0; reg < 4; ++reg) {
          int row = mi * 16 + q * 4 + reg;
          if (row < rows_valid) {
            unsigned int p0 = ((unsigned int)f2bf(acc[1][reg] + bias[1]) << 16) |
                              f2bf(acc[0][reg] + bias[0]);
            unsigned int p1 = ((unsigned int)f2bf(acc[3][reg] + bias[3]) << 16) |
                              f2bf(acc[2][reg] + bias[2]);
            uint2 u; u.x = p0; u.y = p1;
            *reinterpret_cast<uint2*>(
                mdir + (size_t)(beg + tile0 + row) * DIM + nb + lm * 4) = u;
          }
        }
      }
    }
  };

  // ---- pipeline prologue -------------------------------------------------
  if (tid < 64) s_src[0][tid] = load_idx(t);
  __syncthreads();
  issue_stage(0);
  if (tid < 64 && t + GX < ntiles) s_src[1][tid] = load_idx(t + GX);

  // ---- main loop, parity unrolled ---------------------------------------
  while (true) {
    step(0);
    t += GX; if (t >= ntiles) break;
    step(1);
    t += GX; if (t >= ntiles) break;
  }
}

// ---- K6: CSR gather-sum, ONE WAVE PER NODE, no LDS, no barriers ----------

__global__ void reduce_both_kernel(const unsigned short* __restrict__ msg,
                                   const int* __restrict__ rp,
                                   const int* __restrict__ colf,
                                   const int* __restrict__ colr,
                                   float* __restrict__ out) {
  const int n = blockIdx.x * 4 + (threadIdx.x >> 6);
  if (n >= N_NODES) return;
  const int lane = threadIdx.x & 63;
  const int b0 = rp[n], e0 = rp[n + 1];
  const int b1 = rp[(N_NODES + 1) + n], e1 = rp[(N_NODES + 1) + n + 1];
  if (e0 == b0 && e1 == b1) return;

  float a0 = 0.f, a1 = 0.f, a2 = 0.f, a3 = 0.f;
  union { unsigned int u; float f; } c;

  int j = b0;
  for (; j + 1 < e0; j += 2) {  // 2-way unroll: two independent load chains
    int r0 = colf[j], r1 = colf[j + 1];
    uint2 v0 = *reinterpret_cast<const uint2*>(msg + (size_t)r0 * DIM + lane * 4);
    uint2 v1 = *reinterpret_cast<const uint2*>(msg + (size_t)r1 * DIM + lane * 4);
    c.u = v0.x << 16;          a0 += c.f;
    c.u = v0.x & 0xffff0000u;  a1 += c.f;
    c.u = v0.y << 16;          a2 += c.f;
    c.u = v0.y & 0xffff0000u;  a3 += c.f;
    c.u = v1.x << 16;          a0 += c.f;
    c.u = v1.x & 0xffff0000u;  a1 += c.f;
    c.u = v1.y << 16;          a2 += c.f;
    c.u = v1.y & 0xffff0000u;  a3 += c.f;
  }
  if (j < e0) {
    uint2 v = *reinterpret_cast<const uint2*>(msg + (size_t)colf[j] * DIM + lane * 4);
    c.u = v.x << 16;          a0 += c.f;
    c.u = v.x & 0xffff0000u;  a1 += c.f;
    c.u = v.y << 16;          a2 += c.f;
    c.u = v.y & 0xffff0000u;  a3 += c.f;
  }
  const unsigned short* mrev = msg + (size_t)N_EDGES * DIM;
  j = b1;
  for (; j + 1 < e1; j += 2) {
    int r0 = colr[j], r1 = colr[j + 1];
    uint2 v0 = *reinterpret_cast<const uint2*>(mrev + (size_t)r0 * DIM + lane * 4);
    uint2 v1 = *reinterpret_cast<const uint2*>(mrev + (size_t)r1 * DIM + lane * 4);
    c.u = v0.x << 16;          a0 += c.f;
    c.u = v0.x & 0xffff0000u;  a1 += c.f;
    c.u = v0.y << 16;          a2 += c.f;
    c.u = v0.y & 0xffff0000u;  a3 += c.f;
    c.u = v1.x << 16;          a0 += c.f;
    c.u = v1.x & 0xffff0000u;  a1 += c.f;
    c.u = v1.y << 16;          a2 += c.f;
    c.u = v1.y & 0xffff0000u;  a3 += c.f;
  }
  if (j < e1) {
    uint2 v = *reinterpret_cast<const uint2*>(mrev + (size_t)colr[j] * DIM + lane * 4);
    c.u = v.x << 16;          a0 += c.f;
    c.u = v.x & 0xffff0000u;  a1 += c.f;
    c.u = v.y << 16;          a2 += c.f;
    c.u = v.y & 0xffff0000u;  a3 += c.f;
  }

  // invert the storage permutation: short i of this lane's uint2 is column
  // (lane>>4)*64 + i*16 + (lane&15)
  const int cb = (lane >> 4) * 64 + (lane & 15);
  float* op = out + (size_t)n * DIM;
  op[cb +  0] += a0;
  op[cb + 16] += a1;
  op[cb + 32] += a2;
  op[cb + 48] += a3;
}

// ---- fallback: single-phase atomic scatter (if ws too small) -------------

__global__ __launch_bounds__(256, 2)
void self_gemm_kernel(const unsigned short* __restrict__ xbf,
                      const unsigned short* __restrict__ wt_self,
                      const float* __restrict__ b_self,
                      float* __restrict__ out) {
  const int tid = threadIdx.x;
  const int wave = tid >> 6, lane = tid & 63;
  const int lm = lane & 15, q = lane >> 4;
  const int nb = wave * 64;

  bf16x8 wf[8][4];
  #pragma unroll
  for (int kk = 0; kk < 8; ++kk)
    #pragma unroll
    for (int ni = 0; ni < 4; ++ni)
      wf[kk][ni] = *reinterpret_cast<const bf16x8*>(
          wt_self + (size_t)(nb + ni * 16 + lm) * DIM + kk * 32 + q * 8);

  float bias[4];
  #pragma unroll
  for (int ni = 0; ni < 4; ++ni) bias[ni] = b_self[nb + ni * 16 + lm];

  const int ntiles = (N_NODES + 63) / 64;
  for (int t = blockIdx.x; t < ntiles; t += gridDim.x) {
    const int row0 = t * 64;
    const unsigned short* xr[4];
    #pragma unroll
    for (int mi = 0; mi < 4; ++mi) {
      int r = row0 + mi * 16 + lm;
      int rc = r < N_NODES ? r : N_NODES - 1;
      xr[mi] = xbf + (size_t)rc * DIM + q * 8;
    }

    f32x4 acc[4][4];
    #pragma unroll
    for (int mi = 0; mi < 4; ++mi)
      #pragma unroll
      for (int ni = 0; ni < 4; ++ni)
        acc[mi][ni] = (f32x4){0.f, 0.f, 0.f, 0.f};

    #pragma unroll
    for (int kk = 0; kk < 8; ++kk) {
      bf16x8 a[4];
      #pragma unroll
      for (int mi = 0; mi < 4; ++mi)
        a[mi] = *reinterpret_cast<const bf16x8*>(xr[mi] + kk * 32);
      #pragma unroll
      for (int mi = 0; mi < 4; ++mi)
        #pragma unroll
        for (int ni = 0; ni < 4; ++ni)
          acc[mi][ni] = __builtin_amdgcn_mfma_f32_16x16x32_bf16(a[mi], wf[kk][ni], acc[mi][ni], 0, 0, 0);
    }

    #pragma unroll
    for (int mi = 0; mi < 4; ++mi) {
      #pragma unroll
      for (int reg = 0; reg < 4; ++reg) {
        int row = row0 + mi * 16 + q * 4 + reg;
        if (row < N_NODES) {
          #pragma unroll
          for (int ni = 0; ni < 4; ++ni)
            out[(size_t)row * DIM + nb + ni * 16 + lm] = acc[mi][ni][reg] + bias[ni];
        }
      }
    }
  }
}

__global__ void edge_gemm_atomic_kernel(const unsigned short* __restrict__ xbf,
                                        const unsigned short* __restrict__ wt,
                                        const float* __restrict__ b_fwd,
                                        const float* __restrict__ b_rev,
                                        const int* __restrict__ perm,
                                        const int* __restrict__ rel_start,
                                        const int* __restrict__ dep,
                                        const int* __restrict__ gov,
                                        float* __restrict__ out) {
  const int bucket = blockIdx.y;
  const int r = bucket % N_REL;
  const bool fwd = bucket < N_REL;
  const int beg = rel_start[r];
  const int cnt = rel_start[r + 1] - beg;
  const int ntiles = (cnt + 63) >> 6;

  const int tid = threadIdx.x;
  const int wave = tid >> 6, lane = tid & 63;
  const int lm = lane & 15, q = lane >> 4;
  const int nb = wave * 64;

  __shared__ int s_src[64], s_dst[64];

  const unsigned short* wr[4];
  #pragma unroll
  for (int ni = 0; ni < 4; ++ni)
    wr[ni] = wt + (size_t)bucket * DIM * DIM + (size_t)(nb + ni * 16 + lm) * DIM + q * 8;

  const float* bptr = (fwd ? b_fwd : b_rev) + r * DIM;
  float bias[4];
  #pragma unroll
  for (int ni = 0; ni < 4; ++ni) bias[ni] = bptr[nb + ni * 16 + lm];

  for (int t = blockIdx.x; t < ntiles; t += gridDim.x) {
    const int tile0 = t << 6;
    const int rows_valid = min(64, cnt - tile0);

    if (tid < 64) {
      int s = 0, d = -1;
      if (tid < rows_valid) {
        int e = perm[beg + tile0 + tid];
        int gv = gov[e], dp = dep[e];
        s = fwd ? gv : dp;
        d = fwd ? dp : gv;
      }
      s_src[tid] = s;
      s_dst[tid] = d;
    }
    __syncthreads();

    const unsigned short* xr[4];
    #pragma unroll
    for (int mi = 0; mi < 4; ++mi)
      xr[mi] = xbf + (size_t)s_src[mi * 16 + lm] * DIM + q * 8;

    f32x4 acc[4][4];
    #pragma unroll
    for (int mi = 0; mi < 4; ++mi)
      #pragma unroll
      for (int ni = 0; ni < 4; ++ni)
        acc[mi][ni] = (f32x4){0.f, 0.f, 0.f, 0.f};

    #pragma unroll
    for (int k0 = 0; k0 < DIM; k0 += 32) {
      bf16x8 a[4], b[4];
      #pragma unroll
      for (int mi = 0; mi < 4; ++mi) a[mi] = *reinterpret_cast<const bf16x8*>(xr[mi] + k0);
      #pragma unroll
      for (int ni = 0; ni < 4; ++ni) b[ni] = *reinterpret_cast<const bf16x8*>(wr[ni] + k0);
      #pragma unroll
      for (int mi = 0; mi < 4; ++mi)
        #pragma unroll
        for (int ni = 0; ni < 4; ++ni)
          acc[mi][ni] = __builtin_amdgcn_mfma_f32_16x16x32_bf16(a[mi], b[ni], acc[mi][ni], 0, 0, 0);
    }

    #pragma unroll
    for (int mi = 0; mi < 4; ++mi) {
      #pragma unroll
      for (int reg = 0; reg < 4; ++reg) {
        int row = mi * 16 + q * 4 + reg;
        if (row < rows_valid) {
          int dst = s_dst[row];
          float* op = out + (size_t)dst * DIM + nb + lm;
          #pragma unroll
          for (int ni = 0; ni < 4; ++ni)
            atomicAdd(op + ni * 16, acc[mi][ni][reg] + bias[ni]);
        }
      }
    }
    __syncthreads();
  }
}

// ---- launch --------------------------------------------------------------

extern "C" void kernel_launch(void* const* d_in, const int* in_sizes, int n_in,
                              void* d_out, int out_size, void* d_ws, size_t ws_size,
                              hipStream_t stream) {
  const float* x      = (const float*)d_in[0];
  const float* W_self = (const float*)d_in[1];
  const float* b_self = (const float*)d_in[2];
  const float* W_fwd  = (const float*)d_in[3];
  const float* b_fwd  = (const float*)d_in[4];
  const float* W_rev  = (const float*)d_in[5];
  const float* b_rev  = (const float*)d_in[6];
  const int* dep = (const int*)d_in[7];
  const int* rel = (const int*)d_in[8];
  const int* gov = (const int*)d_in[9];
  float* out = (float*)d_out;

  char* base = (char*)d_ws;
  size_t off = 0;
  auto alloc = [&](size_t bytes) -> char* {
    char* p = base + off;
    off = (off + bytes + 15) & ~(size_t)15;
    return p;
  };

  unsigned short* xbf = (unsigned short*)alloc((size_t)N_NODES * DIM * 2);   // 15.36 MB
  unsigned short* wt  = (unsigned short*)alloc((size_t)21 * DIM * DIM * 2);  // 2.75 MB
  int* perm          = (int*)alloc((size_t)N_EDGES * 4);
  int* srcf          = (int*)alloc((size_t)N_EDGES * 4);
  int* srcr          = (int*)alloc((size_t)N_EDGES * 4);
  int* rel_start     = (int*)alloc(16 * 4);
  int* block_counts  = (int*)alloc(SORT_BLOCKS * N_REL * 4);
  int* block_offset  = (int*)alloc(SORT_BLOCKS * N_REL * 4);
  int* cnt       = (int*)alloc((size_t)2 * N_NODES * 4);
  int* tmp       = (int*)alloc((size_t)2 * N_NODES * 4);
  int* sums      = (int*)alloc((size_t)2 * SCAN_BLOCKS * 4);
  int* rp        = (int*)alloc((size_t)2 * (N_NODES + 1) * 4);
  int* cursor    = (int*)alloc((size_t)2 * N_NODES * 4);
  int* colf      = (int*)alloc((size_t)N_EDGES * 4);
  int* colr      = (int*)alloc((size_t)N_EDGES * 4);
  unsigned short* msg = (unsigned short*)alloc((size_t)2 * N_EDGES * DIM * 2);  // 153.6 MB
  const bool two_phase = (off <= ws_size);

  hipMemsetAsync(cnt, 0, (size_t)2 * N_NODES * 4, stream);
  prep_hist_kernel<<<PREP_XB + PREP_WB + SORT_BLOCKS, 256, 0, stream>>>(
      x, W_fwd, W_rev, W_self, rel, dep, gov, xbf, wt, block_counts, cnt);
  scanA_kernel<<<dim3(SCAN_BLOCKS, 2), SCAN_CHUNK, 0, stream>>>(cnt, tmp, sums);
  scan_finish_kernel<<<dim3(SCAN_BLOCKS + 1, 2), SCAN_CHUNK, 0, stream>>>(
      sums, tmp, block_counts, rp, cursor, rel_start, block_offset);
  scatter_all_kernel<<<SORT_BLOCKS, 256, 0, stream>>>(
      rel, dep, gov, block_offset, cursor, perm, srcf, srcr, colf, colr);

  if (two_phase) {
    // buckets 0..19 edges -> msg; buckets 20/21 self halves -> out
    mega_gemm_kernel<<<dim3(48, 2 * N_REL + 2), 256, 0, stream>>>(
        xbf, wt, b_self, b_fwd, b_rev, srcf, srcr, rel_start, msg, out);
    reduce_both_kernel<<<(N_NODES + 3) / 4, 256, 0, stream>>>(
        msg, rp, colf, colr, out);
  } else {
    self_gemm_kernel<<<120, 256, 0, stream>>>(
        xbf, wt + (size_t)20 * DIM * DIM, b_self, out);
    edge_gemm_atomic_kernel<<<dim3(260, 20), 256, 0, stream>>>(
        xbf, wt, b_fwd, b_rev, perm, rel_start, dep, gov, out);
  }
}